// Round 14
// baseline (21.153 us; speedup 1.0000x reference)
//
#include <hip/hip_runtime.h>
#include <hip/hip_fp16.h>

// GaussianVideo3D2D: N gaussians -> (T=4, H=128, W=128, C=3) fp32 volume.
// R14 restructure: 1024 blocks (4t x 64 two-row slabs x 4 x-quarters) x
// 512 thr (8 waves). Rationale: 1024-thr blocks pin occupancy at 16 waves/CU
// (>64 VGPR) with a hard 128-VGPR ceiling; 512-thr blocks reach 24 waves/CU
// (3 blocks) at <=85 VGPR. Lean-register design: single chain/lane, 8 px as
// f32x2-packed PIXEL-PAIRS (acc 24 regs, not 48):
//   e2 = {e(x0),e(x1)}; pair-step ratio rr2 = {exp2(d0+d1), exp2(d1+d2)};
//   rr2 *= ss (= exp2(8A*DX^2), stored); e2 *= rr2 -> advances 2 px.
// Tile culling is now real: x-max clamped to the block's 32-px window ->
// keep-rate ~50-70% (was ~95% at full rows), cutting total pair work.
// Prep: 2 gaussians/thread (2 ballot-compaction rounds, order-preserving).
// record = {gy0, gy1, h0, h1 | A, ss, rg(f16x2), fb}; gy_r = C y_r + Dx,
// h_r = (B y_r + Dy) y_r + E (log2 domain, -0.5*log2e + log2(alpha) folded).

#define GV_H 128
#define GV_W 128
#define GV_T 4
#define GV_NMAX 1024
#define GV_DX 0.015625f                       // 2/128
#define K_HALF_LOG2E (-0.72134752044448170f)  // -0.5 * log2(e)
#define GV_LOG2E 1.44269504088896340f
#define U_CULL (-20.0f)

typedef float f32x2 __attribute__((ext_vector_type(2)));

__device__ __forceinline__ float fexp2(float x) { return __builtin_amdgcn_exp2f(x); }
__device__ __forceinline__ float frcp(float x)  { return __builtin_amdgcn_rcpf(x); }
__device__ __forceinline__ float flog2(float x) { return __builtin_amdgcn_logf(x); }

__device__ __forceinline__ float fast_tanh(float x) {
    float t = fexp2(2.885390082f * x);
    return fmaf(-2.0f, frcp(t + 1.0f), 1.0f);
}

__global__ __launch_bounds__(512, 3) void gv_fused_kernel(
    const float* __restrict__ xyz, const float* __restrict__ chol,
    const float* __restrict__ feats, const float* __restrict__ opac,
    float* __restrict__ out, int N)
{
    __shared__ __align__(16) float stab[GV_NMAX * 8];   // 32 KB records
    __shared__ int swt[16];

    int b    = blockIdx.x;        // [t(2b) | slab(6b) | xq(2b)]
    int xq   = b & 3;
    int slab = (b >> 2) & 63;
    int t    = b >> 8;
    int tid  = threadIdx.x;
    int wv   = tid >> 6;          // 0..7
    int lane = tid & 63;

    float y0r = ((float)(slab * 2) + 0.5f) * GV_DX - 1.0f;
    float y1r = y0r + GV_DX;
    float xlo = ((float)(xq * 32) + 0.5f) * GV_DX - 1.0f;   // tile x window
    float xhi = xlo + 31.0f * GV_DX;

    // ------------- Phase 1: prep + tile-cull (2 gaussians / thread) --------
    float4 rec0[2], rec1[2];
    bool keep[2];
    unsigned long long bm[2];

    #pragma unroll
    for (int r = 0; r < 2; ++r) {
        keep[r] = false;
        rec0[r] = make_float4(0.f, 0.f, -1e30f, -1e30f);
        rec1[r] = make_float4(0.f, 0.f, 0.f, 0.f);
        int n = r * 512 + tid;
        if (n < N) {
            float mx = fast_tanh(xyz[n * 3 + 0]);
            float my = fast_tanh(xyz[n * 3 + 1]);
            float mt = fast_tanh(xyz[n * 3 + 2]);

            const float sc = 2.0f * 16.0f / (float)GV_W;  // SCALE = 0.25
            float L00 = sc * (chol[n * 6 + 0] + 0.5f);
            float L10 = sc * (chol[n * 6 + 1]);
            float L20 = sc * (chol[n * 6 + 2]);
            float L11 = sc * (chol[n * 6 + 3] + 0.5f);
            float L21 = sc * (chol[n * 6 + 4]);
            float L22 = sc * (chol[n * 6 + 5] + 0.5f);

            float il0 = frcp(L00), il1 = frcp(L11), il2 = frcp(L22);
            float m10 = -L10 * il0 * il1;
            float m21 = -L21 * il1 * il2;
            float m20 = (L10 * L21 - L11 * L20) * (il0 * il1 * il2);
            float a   = il0 * il0 + m10 * m10 + m20 * m20;
            float sab = m10 * il1 + m20 * m21;
            float sat = m20 * il2;
            float bb  = il1 * il1 + m21 * m21;
            float sbt = m21 * il2;
            float cc  = il2 * il2;
            float ab2 = 2.0f * sab, at2 = 2.0f * sat, bt2 = 2.0f * sbt;

            float o = opac[n];
            float bias = -flog2(1.0f + fexp2(-GV_LOG2E * o));

            float tv = ((float)t + 0.5f) * (2.0f / (float)GV_T) - 1.0f;
            float dt = tv - mt;

            const float k = K_HALF_LOG2E;
            float A  = k * a;
            float B  = k * bb;
            float C  = k * ab2;
            float Dx = k * (at2 * dt - 2.0f * a * mx - ab2 * my);
            float Dy = k * (bt2 * dt - 2.0f * bb * my - ab2 * mx);
            float E  = k * (a * mx * mx + bb * my * my + cc * dt * dt
                            + ab2 * mx * my - at2 * mx * dt - bt2 * my * dt)
                       + bias;

            float gy0 = fmaf(C, y0r, Dx);
            float gy1 = fmaf(C, y1r, Dx);
            float h0  = fmaf(fmaf(B, y0r, Dy), y0r, E);
            float h1  = fmaf(fmaf(B, y1r, Dy), y1r, E);
            float ss  = fexp2(A * (8.0f * GV_DX * GV_DX));  // pair-step ratio

            float fr = feats[n * 3 + 0];
            float fg = feats[n * 3 + 1];
            float fb = feats[n * 3 + 2];
            unsigned hr = (unsigned)__half_as_ushort(__float2half_rn(fr))
                        | ((unsigned)__half_as_ushort(__float2half_rn(fg)) << 16);
            float rgbits = __uint_as_float(hr);

            // exact tile-max of u over the 2 rows, x clamped to tile window
            float inv2A = 0.5f * frcp(A);   // A < 0 always
            float xs0 = fminf(fmaxf(-gy0 * inv2A, xlo), xhi);
            float xs1 = fminf(fmaxf(-gy1 * inv2A, xlo), xhi);
            float u0  = fmaf(fmaf(A, xs0, gy0), xs0, h0);
            float u1  = fmaf(fmaf(A, xs1, gy1), xs1, h1);
            keep[r] = (fmaxf(u0, u1) > U_CULL);

            rec0[r] = make_float4(gy0, gy1, h0, h1);
            rec1[r] = make_float4(A, ss, rgbits, fb);
        }
        bm[r] = __ballot((int)keep[r]);
    }

    if (lane == 0) {
        swt[wv]     = (int)__popcll(bm[0]);
        swt[8 + wv] = (int)__popcll(bm[1]);
    }
    __syncthreads();

    int M = 0, base0 = 0, base1 = 0;
    #pragma unroll
    for (int k2 = 0; k2 < 16; ++k2) {
        int c = swt[k2];
        if (k2 < wv)     base0 += c;
        if (k2 < 8 + wv) base1 += c;
        M += c;
    }
    unsigned long long lmask = (1ull << lane) - 1ull;
    if (keep[0]) {
        float4* dst = (float4*)&stab[(base0 + (int)__popcll(bm[0] & lmask)) * 8];
        dst[0] = rec0[0]; dst[1] = rec1[0];
    }
    if (keep[1]) {
        float4* dst = (float4*)&stab[(base1 + (int)__popcll(bm[1] & lmask)) * 8];
        dst[0] = rec0[1]; dst[1] = rec1[1];
    }
    int MP = (M + 63) & ~63;      // pad to 64 (8 waves x 8 slots per iter)
    #pragma unroll
    for (int r = 0; r < 2; ++r) {
        int di = r * 512 + tid;
        if (di >= M && di < MP) {
            float4* dst = (float4*)&stab[di * 8];
            dst[0] = make_float4(0.f, 0.f, -1e30f, -1e30f);  // e = 0 always
            dst[1] = make_float4(0.f, 0.f, 0.f, 0.f);
        }
    }
    __syncthreads();

    // ------------- Phase 2: splat (px-pair packed, 8 slots / wave) ---------
    int slot = lane >> 3;         // 0..7 : gaussian slot
    int pg   = lane & 7;          // 4 octs x 2 rows
    int oct  = pg & 3;
    int row  = pg >> 2;

    float x0  = ((float)(xq * 32 + oct * 8) + 0.5f) * GV_DX - 1.0f;
    float caa = 2.0f * x0 + GV_DX;
    const float c2d2 = 2.0f * GV_DX * GV_DX;
    bool r1 = (row == 1);

    f32x2 aR[4], aG[4], aB[4];
    #pragma unroll
    for (int j = 0; j < 4; ++j) {
        aR[j] = (f32x2)(0.f); aG[j] = (f32x2)(0.f); aB[j] = (f32x2)(0.f);
    }

    int iters = MP >> 6;
    const float4* rp = (const float4*)&stab[(wv * 8 + slot) * 8];

    #pragma unroll 1
    for (int it = 0; it < iters; ++it) {
        float4 q0 = rp[0];   // gy0 gy1 h0 h1
        float4 q1 = rp[1];   // A ss rg fb
        rp += 64 * 2;

        float gy = r1 ? q0.y : q0.x;
        float h  = r1 ? q0.w : q0.z;
        float A  = q1.x;

        float u0 = fmaf(fmaf(A, x0, gy), x0, h);
        float d0 = GV_DX * fmaf(A, caa, gy);       // delta(x0): step-DX arg
        float t1 = A * c2d2;                        // 2*A*DX^2
        float p0 = fmaf(2.0f, d0, t1);              // d0 + d1
        float p1 = fmaf(2.0f, t1, p0);              // d1 + d2

        f32x2 e2  = { fexp2(u0), fexp2(u0 + d0) };  // px0, px1
        f32x2 rr2 = { fexp2(p0), fexp2(p1) };       // 2-px-step ratios
        f32x2 ss2 = { q1.y, q1.y };

        unsigned bits = __float_as_uint(q1.z);
        float fr = __half2float(__ushort_as_half((unsigned short)(bits & 0xffffu)));
        float fg = __half2float(__ushort_as_half((unsigned short)(bits >> 16)));
        f32x2 fr2 = { fr, fr };
        f32x2 fg2 = { fg, fg };
        f32x2 fb2 = { q1.w, q1.w };

        #pragma unroll
        for (int j = 0; j < 4; ++j) {
            aR[j] = __builtin_elementwise_fma(e2, fr2, aR[j]);
            aG[j] = __builtin_elementwise_fma(e2, fg2, aG[j]);
            aB[j] = __builtin_elementwise_fma(e2, fb2, aB[j]);
            if (j < 3) { e2 *= rr2; rr2 *= ss2; }
        }
    }

    // ------------- Phase 3: slot butterfly + dump + write ------------------
    #pragma unroll
    for (int j = 0; j < 4; ++j) {
        #pragma unroll
        for (int m = 8; m <= 32; m <<= 1) {
            aR[j][0] += __shfl_xor(aR[j][0], m, 64);
            aR[j][1] += __shfl_xor(aR[j][1], m, 64);
            aG[j][0] += __shfl_xor(aG[j][0], m, 64);
            aG[j][1] += __shfl_xor(aG[j][1], m, 64);
            aB[j][0] += __shfl_xor(aB[j][0], m, 64);
            aB[j][1] += __shfl_xor(aB[j][1], m, 64);
        }
    }

    __syncthreads();  // record reads done; reuse stab for partial dump

    if (slot == 0) {
        // per (wave, pg): 24 floats at stride 26 (bank-decorrelated)
        float* dst = &stab[wv * 208 + pg * 26];
        #pragma unroll
        for (int j = 0; j < 4; ++j) {
            dst[j * 6 + 0] = aR[j][0];
            dst[j * 6 + 1] = aR[j][1];
            dst[j * 6 + 2] = aG[j][0];
            dst[j * 6 + 3] = aG[j][1];
            dst[j * 6 + 4] = aB[j][0];
            dst[j * 6 + 5] = aB[j][1];
        }
    }
    __syncthreads();

    // final: 192 outputs (2 rows x 32 px x 3), coalesced per row
    if (tid < 192) {
        int c   = tid % 3;
        int px  = tid / 3;
        int x   = px & 31;
        int rw  = px >> 5;
        int oc  = x >> 3;
        int p8  = x & 7;
        int j   = p8 >> 1;
        int cmp = p8 & 1;
        int ofs = (rw * 4 + oc) * 26 + j * 6 + c * 2 + cmp;
        float sum = 0.f;
        #pragma unroll
        for (int w = 0; w < 8; ++w) sum += stab[w * 208 + ofs];
        int idx = ((t * GV_H + slab * 2 + rw) * GV_W + xq * 32 + x) * 3 + c;
        out[idx] = fminf(fmaxf(sum, 0.0f), 1.0f);
    }
}

extern "C" void kernel_launch(void* const* d_in, const int* in_sizes, int n_in,
                              void* d_out, int out_size, void* d_ws, size_t ws_size,
                              hipStream_t stream) {
    const float* xyz   = (const float*)d_in[0];
    const float* chol  = (const float*)d_in[1];
    const float* feats = (const float*)d_in[2];
    const float* opac  = (const float*)d_in[3];
    float* out = (float*)d_out;
    int N = in_sizes[0] / 3;
    if (N > GV_NMAX) N = GV_NMAX;  // LDS record capacity (reference N=1024)

    int blocks = GV_T * 64 * 4;    // 1024: 4t x 64 slabs x 4 x-quarters
    gv_fused_kernel<<<blocks, 512, 0, stream>>>(xyz, chol, feats, opac, out, N);
}

// Round 15
// 18.714 us; speedup vs baseline: 1.1304x; 1.1304x over previous
//
#include <hip/hip_runtime.h>
#include <hip/hip_fp16.h>

// GaussianVideo3D2D: N gaussians -> (T=4, H=128, W=128, C=3) fp32 volume.
// R15: 512 blocks (4t x 128 single-row slabs) x 512 thr (8 waves).
// vs R14 (regressed): no x-quartering (prep redundancy back to 2x R11),
// single-row record (1 y-fold) = {gy, h, A, ss | rg, fb} -> 1 b128 + 1 b64
// per gaussian, no row-selects in the prologue.
// Splat: 4 slots (lane>>4) x 16 lanes (lane&15); each lane 8 px of the
// 128-px row as 4 f32x2 PIXEL-PAIRS (acc = 12 VGPR):
//   e2={e(x0),e(x1)}; pair-step rr2={exp2(d0+d1),exp2(d1+d2)}; rr2*=ss
//   (ss=exp2(8A*DX^2) stored); e2*=rr2 advances 2 px.  [verified in R14]
// ILP-2: two record chains (ia, ia+1) per lane, both accumulating into the
// SAME acc -> latency hiding without acc duplication. Per wave-iter:
// 8 gaussians x 128 px = 1024 pairs at ~78 instrs (0.076 wave-instr/pair).
// Occupancy: launch_bounds(512,3) (arg2 = min blocks/CU on this compiler;
// R4's (512,6) 3072-thr overcommit caused the VGPR=32 spill disaster).
// Target 3 blocks/CU = 24 waves/CU (needs <=85 VGPR, est ~70).
// gy = C y + Dx, h = (B y + Dy) y + E (log2 domain, -0.5*log2e and
// log2(alpha) folded); dens = exp2((A x + gy) x + h). Cull: row-max
// u* = u(clamp(-gy/2A)) > -20 (contribution < 2^-20, threshold 2e-2).

#define GV_H 128
#define GV_W 128
#define GV_T 4
#define GV_NMAX 1024
#define GV_DX 0.015625f                       // 2/128
#define K_HALF_LOG2E (-0.72134752044448170f)  // -0.5 * log2(e)
#define GV_LOG2E 1.44269504088896340f
#define U_CULL (-20.0f)

typedef float f32x2 __attribute__((ext_vector_type(2)));

__device__ __forceinline__ float fexp2(float x) { return __builtin_amdgcn_exp2f(x); }
__device__ __forceinline__ float frcp(float x)  { return __builtin_amdgcn_rcpf(x); }
__device__ __forceinline__ float flog2(float x) { return __builtin_amdgcn_logf(x); }

__device__ __forceinline__ float fast_tanh(float x) {
    float t = fexp2(2.885390082f * x);
    return fmaf(-2.0f, frcp(t + 1.0f), 1.0f);
}

__global__ __launch_bounds__(512, 3) void gv_fused_kernel(
    const float* __restrict__ xyz, const float* __restrict__ chol,
    const float* __restrict__ feats, const float* __restrict__ opac,
    float* __restrict__ out, int N)
{
    __shared__ __align__(16) float stab[GV_NMAX * 8];   // 32 KB records/dump
    __shared__ int swt[16];

    int b    = blockIdx.x;        // [t(2b) | row(7b)]
    int slab = b & 127;           // row index
    int t    = b >> 7;
    int tid  = threadIdx.x;
    int wv   = tid >> 6;          // 0..7
    int lane = tid & 63;

    float yr = ((float)slab + 0.5f) * GV_DX - 1.0f;

    // ------------- Phase 1: prep + row-cull (2 gaussians / thread) ---------
    float4 rec0[2];
    float2 rec1[2];
    bool keep[2];
    unsigned long long bm[2];

    #pragma unroll
    for (int r = 0; r < 2; ++r) {
        keep[r] = false;
        rec0[r] = make_float4(0.f, -1e30f, 0.f, 0.f);
        rec1[r] = make_float2(0.f, 0.f);
        int n = r * 512 + tid;
        if (n < N) {
            float mx = fast_tanh(xyz[n * 3 + 0]);
            float my = fast_tanh(xyz[n * 3 + 1]);
            float mt = fast_tanh(xyz[n * 3 + 2]);

            const float sc = 2.0f * 16.0f / (float)GV_W;  // SCALE = 0.25
            float L00 = sc * (chol[n * 6 + 0] + 0.5f);
            float L10 = sc * (chol[n * 6 + 1]);
            float L20 = sc * (chol[n * 6 + 2]);
            float L11 = sc * (chol[n * 6 + 3] + 0.5f);
            float L21 = sc * (chol[n * 6 + 4]);
            float L22 = sc * (chol[n * 6 + 5] + 0.5f);

            float il0 = frcp(L00), il1 = frcp(L11), il2 = frcp(L22);
            float m10 = -L10 * il0 * il1;
            float m21 = -L21 * il1 * il2;
            float m20 = (L10 * L21 - L11 * L20) * (il0 * il1 * il2);
            float a   = il0 * il0 + m10 * m10 + m20 * m20;
            float sab = m10 * il1 + m20 * m21;
            float sat = m20 * il2;
            float bb  = il1 * il1 + m21 * m21;
            float sbt = m21 * il2;
            float cc  = il2 * il2;
            float ab2 = 2.0f * sab, at2 = 2.0f * sat, bt2 = 2.0f * sbt;

            float o = opac[n];
            float bias = -flog2(1.0f + fexp2(-GV_LOG2E * o));

            float tv = ((float)t + 0.5f) * (2.0f / (float)GV_T) - 1.0f;
            float dt = tv - mt;

            const float k = K_HALF_LOG2E;
            float A  = k * a;
            float B  = k * bb;
            float C  = k * ab2;
            float Dx = k * (at2 * dt - 2.0f * a * mx - ab2 * my);
            float Dy = k * (bt2 * dt - 2.0f * bb * my - ab2 * mx);
            float E  = k * (a * mx * mx + bb * my * my + cc * dt * dt
                            + ab2 * mx * my - at2 * mx * dt - bt2 * my * dt)
                       + bias;

            float gy = fmaf(C, yr, Dx);
            float h  = fmaf(fmaf(B, yr, Dy), yr, E);
            float ss = fexp2(A * (8.0f * GV_DX * GV_DX));  // pair-step ratio

            float fr = feats[n * 3 + 0];
            float fg = feats[n * 3 + 1];
            float fb = feats[n * 3 + 2];
            unsigned hr = (unsigned)__half_as_ushort(__float2half_rn(fr))
                        | ((unsigned)__half_as_ushort(__float2half_rn(fg)) << 16);

            // exact row-max of u (concave in x, A < 0)
            float inv2A = 0.5f * frcp(A);
            float xs = fminf(fmaxf(-gy * inv2A, -1.0f), 1.0f);
            float u  = fmaf(fmaf(A, xs, gy), xs, h);
            keep[r] = (u > U_CULL);

            rec0[r] = make_float4(gy, h, A, ss);
            rec1[r] = make_float2(__uint_as_float(hr), fb);
        }
        bm[r] = __ballot((int)keep[r]);
    }

    if (lane == 0) {
        swt[wv]     = (int)__popcll(bm[0]);
        swt[8 + wv] = (int)__popcll(bm[1]);
    }
    __syncthreads();

    int M = 0, base0 = 0, base1 = 0;
    #pragma unroll
    for (int k2 = 0; k2 < 16; ++k2) {
        int c = swt[k2];
        if (k2 < wv)     base0 += c;
        if (k2 < 8 + wv) base1 += c;
        M += c;
    }
    unsigned long long lmask = (1ull << lane) - 1ull;
    if (keep[0]) {
        int di = base0 + (int)__popcll(bm[0] & lmask);
        *(float4*)&stab[di * 8]     = rec0[0];
        *(float2*)&stab[di * 8 + 4] = rec1[0];
    }
    if (keep[1]) {
        int di = base1 + (int)__popcll(bm[1] & lmask);
        *(float4*)&stab[di * 8]     = rec0[1];
        *(float2*)&stab[di * 8 + 4] = rec1[1];
    }
    int MP = (M + 63) & ~63;      // pad: 64 gaussians consumed per iter
    #pragma unroll
    for (int r = 0; r < 2; ++r) {
        int di = r * 512 + tid;
        if (di >= M && di < MP) {
            *(float4*)&stab[di * 8]     = make_float4(0.f, -1e30f, 0.f, 0.f);
            *(float2*)&stab[di * 8 + 4] = make_float2(0.f, 0.f);
        }
    }
    __syncthreads();

    // ------------- Phase 2: splat (4 slots x 16 lanes, ILP-2) --------------
    int slot = lane >> 4;         // 0..3 : gaussian slot pair
    int li   = lane & 15;         // 16 lanes x 8 px = 128-px row

    float x0  = ((float)(li * 8) + 0.5f) * GV_DX - 1.0f;
    float caa = 2.0f * x0 + GV_DX;
    const float c2d2 = 2.0f * GV_DX * GV_DX;

    f32x2 aR[4], aG[4], aB[4];
    #pragma unroll
    for (int j = 0; j < 4; ++j) {
        aR[j] = (f32x2)(0.f); aG[j] = (f32x2)(0.f); aB[j] = (f32x2)(0.f);
    }

    int iters = MP >> 6;          // 8 waves x 4 slots x 2 chains = 64 / iter
    const float* rp = &stab[(wv * 8 + slot * 2) * 8];

    #pragma unroll 1
    for (int it = 0; it < iters; ++it) {
        float4 qa0 = *(const float4*)(rp);          // gy h A ss
        float2 qa1 = *(const float2*)(rp + 4);      // rg fb
        float4 qb0 = *(const float4*)(rp + 8);
        float2 qb1 = *(const float2*)(rp + 12);
        rp += 64 * 8;

        // chain a prologue
        float u0a = fmaf(fmaf(qa0.z, x0, qa0.x), x0, qa0.y);
        float d0a = GV_DX * fmaf(qa0.z, caa, qa0.x);
        float t1a = qa0.z * c2d2;
        float p0a = fmaf(2.0f, d0a, t1a);
        float p1a = fmaf(2.0f, t1a, p0a);
        f32x2 ea2  = { fexp2(u0a), fexp2(u0a + d0a) };
        f32x2 rra2 = { fexp2(p0a), fexp2(p1a) };
        f32x2 ssa2 = { qa0.w, qa0.w };
        unsigned bia = __float_as_uint(qa1.x);
        float fra = __half2float(__ushort_as_half((unsigned short)(bia & 0xffffu)));
        float fga = __half2float(__ushort_as_half((unsigned short)(bia >> 16)));
        f32x2 fra2 = { fra, fra }, fga2 = { fga, fga };
        f32x2 fba2 = { qa1.y, qa1.y };

        // chain b prologue
        float u0b = fmaf(fmaf(qb0.z, x0, qb0.x), x0, qb0.y);
        float d0b = GV_DX * fmaf(qb0.z, caa, qb0.x);
        float t1b = qb0.z * c2d2;
        float p0b = fmaf(2.0f, d0b, t1b);
        float p1b = fmaf(2.0f, t1b, p0b);
        f32x2 eb2  = { fexp2(u0b), fexp2(u0b + d0b) };
        f32x2 rrb2 = { fexp2(p0b), fexp2(p1b) };
        f32x2 ssb2 = { qb0.w, qb0.w };
        unsigned bib = __float_as_uint(qb1.x);
        float frb = __half2float(__ushort_as_half((unsigned short)(bib & 0xffffu)));
        float fgb = __half2float(__ushort_as_half((unsigned short)(bib >> 16)));
        f32x2 frb2 = { frb, frb }, fgb2 = { fgb, fgb };
        f32x2 fbb2 = { qb1.y, qb1.y };

        #pragma unroll
        for (int j = 0; j < 4; ++j) {
            aR[j] = __builtin_elementwise_fma(ea2, fra2, aR[j]);
            aG[j] = __builtin_elementwise_fma(ea2, fga2, aG[j]);
            aB[j] = __builtin_elementwise_fma(ea2, fba2, aB[j]);
            aR[j] = __builtin_elementwise_fma(eb2, frb2, aR[j]);
            aG[j] = __builtin_elementwise_fma(eb2, fgb2, aG[j]);
            aB[j] = __builtin_elementwise_fma(eb2, fbb2, aB[j]);
            if (j < 3) {
                ea2 *= rra2; rra2 *= ssa2;
                eb2 *= rrb2; rrb2 *= ssb2;
            }
        }
    }

    // ------------- Phase 3: slot butterfly + dump + write ------------------
    #pragma unroll
    for (int j = 0; j < 4; ++j) {
        #pragma unroll
        for (int m = 16; m <= 32; m <<= 1) {
            aR[j][0] += __shfl_xor(aR[j][0], m, 64);
            aR[j][1] += __shfl_xor(aR[j][1], m, 64);
            aG[j][0] += __shfl_xor(aG[j][0], m, 64);
            aG[j][1] += __shfl_xor(aG[j][1], m, 64);
            aB[j][0] += __shfl_xor(aB[j][0], m, 64);
            aB[j][1] += __shfl_xor(aB[j][1], m, 64);
        }
    }

    __syncthreads();  // all record reads done; reuse stab for partial dump

    if (slot == 0) {
        // per (wave, li): 24 floats at stride 25 (coprime 32 banks)
        float* dst = &stab[wv * 400 + li * 25];
        #pragma unroll
        for (int j = 0; j < 4; ++j) {
            dst[j * 6 + 0] = aR[j][0];
            dst[j * 6 + 1] = aR[j][1];
            dst[j * 6 + 2] = aG[j][0];
            dst[j * 6 + 3] = aG[j][1];
            dst[j * 6 + 4] = aB[j][0];
            dst[j * 6 + 5] = aB[j][1];
        }
    }
    __syncthreads();

    // final: 384 outputs (128 px x 3), coalesced contiguous row write
    if (tid < GV_W * 3) {
        int c   = tid % 3;
        int px  = tid / 3;
        int li2 = px >> 3;
        int p8  = px & 7;
        int j   = p8 >> 1;
        int cmp = p8 & 1;
        int ofs = li2 * 25 + j * 6 + c * 2 + cmp;
        float sum = 0.f;
        #pragma unroll
        for (int w = 0; w < 8; ++w) sum += stab[w * 400 + ofs];
        int idx = ((t * GV_H + slab) * GV_W + px) * 3 + c;
        out[idx] = fminf(fmaxf(sum, 0.0f), 1.0f);
    }
}

extern "C" void kernel_launch(void* const* d_in, const int* in_sizes, int n_in,
                              void* d_out, int out_size, void* d_ws, size_t ws_size,
                              hipStream_t stream) {
    const float* xyz   = (const float*)d_in[0];
    const float* chol  = (const float*)d_in[1];
    const float* feats = (const float*)d_in[2];
    const float* opac  = (const float*)d_in[3];
    float* out = (float*)d_out;
    int N = in_sizes[0] / 3;
    if (N > GV_NMAX) N = GV_NMAX;  // LDS record capacity (reference N=1024)

    int blocks = GV_T * GV_H;      // 512: 4t x 128 rows
    gv_fused_kernel<<<blocks, 512, 0, stream>>>(xyz, chol, feats, opac, out, N);
}

// Round 16
// 17.141 us; speedup vs baseline: 1.2341x; 1.0917x over previous
//
#include <hip/hip_runtime.h>
#include <hip/hip_fp16.h>

// GaussianVideo3D2D: N gaussians -> (T=4, H=128, W=128, C=3) fp32 volume.
// FINAL (R16 = revert to R11, the best measured variant: 17.1 us).
// Structure: 256 blocks (64 two-row slabs x 4 t) x 1024 thr (16 waves),
// block-local; prep fused; per-block cull; ILP-2 + packed-f32 j-loop;
// all y-dependence folded into prep:
//   record = {A, gy0, gy1, h0 | h1, s, rg(f16x2), fb}
//   gy_r = C y_r + Dx, h_r = (B y_r + Dy) y_r + E, s = exp2(2A DX^2).
// dens = exp2((A x + gy) x + h), log2 domain (-0.5*log2e, log2(alpha)
// folded). 8-px x-runs via e*=r, r*=s recurrence (flush-safe).
// Structure-space results (R12-R15: row-pack / 512-thr / x-quarter /
// lean-record all regressed to 17.6-21.2): this is the plateau point where
// VALU issue, 2-way LDS broadcast, and ~4us fixed overhead balance.

#define GV_H 128
#define GV_W 128
#define GV_T 4
#define GV_NMAX 1024
#define GV_DX 0.015625f                       // 2/128
#define K_HALF_LOG2E (-0.72134752044448170f)  // -0.5 * log2(e)
#define GV_LOG2E 1.44269504088896340f
#define U_CULL (-20.0f)

typedef float f32x2 __attribute__((ext_vector_type(2)));

__device__ __forceinline__ float fexp2(float x) { return __builtin_amdgcn_exp2f(x); }
__device__ __forceinline__ float frcp(float x)  { return __builtin_amdgcn_rcpf(x); }
__device__ __forceinline__ float flog2(float x) { return __builtin_amdgcn_logf(x); }

__device__ __forceinline__ float fast_tanh(float x) {
    float t = fexp2(2.885390082f * x);
    return fmaf(-2.0f, frcp(t + 1.0f), 1.0f);
}

__global__ __launch_bounds__(1024) void gv_fused_kernel(
    const float* __restrict__ xyz, const float* __restrict__ chol,
    const float* __restrict__ feats, const float* __restrict__ opac,
    float* __restrict__ out, int N)
{
    // records: up to 1024*8 = 8192 floats; dump: 512 slots * 25 = 12800
    __shared__ __align__(16) float stab[12800];   // 51.2 KB
    __shared__ int swt[16];

    int b    = blockIdx.x;   // 0..255: [t(2b) | slab(6b)]
    int slab = b & 63;
    int t    = b >> 6;
    int tid  = threadIdx.x;
    int wv   = tid >> 6;
    int lane = tid & 63;

    float y0r = ((float)(slab * 2) + 0.5f) * GV_DX - 1.0f;  // row 0 y
    float y1r = y0r + GV_DX;                                // row 1 y

    // ---------------- Phase 1: prep + cull (1 gaussian / thread) -----------
    float A = 0.f, gy0 = 0.f, gy1 = 0.f, h0 = 0.f, h1 = 0.f, sv = 0.f;
    float rgbits = 0.f, fb = 0.f;
    bool keep = false;

    if (tid < N) {
        int n = tid;
        float mx = fast_tanh(xyz[n * 3 + 0]);
        float my = fast_tanh(xyz[n * 3 + 1]);
        float mt = fast_tanh(xyz[n * 3 + 2]);

        const float sc = 2.0f * 16.0f / (float)GV_W;  // SCALE = 0.25
        float L00 = sc * (chol[n * 6 + 0] + 0.5f);
        float L10 = sc * (chol[n * 6 + 1]);
        float L20 = sc * (chol[n * 6 + 2]);
        float L11 = sc * (chol[n * 6 + 3] + 0.5f);
        float L21 = sc * (chol[n * 6 + 4]);
        float L22 = sc * (chol[n * 6 + 5] + 0.5f);

        float il0 = frcp(L00), il1 = frcp(L11), il2 = frcp(L22);
        float m10 = -L10 * il0 * il1;
        float m21 = -L21 * il1 * il2;
        float m20 = (L10 * L21 - L11 * L20) * (il0 * il1 * il2);
        float a   = il0 * il0 + m10 * m10 + m20 * m20;
        float sab = m10 * il1 + m20 * m21;
        float sat = m20 * il2;
        float bb  = il1 * il1 + m21 * m21;
        float sbt = m21 * il2;
        float cc  = il2 * il2;
        float ab2 = 2.0f * sab, at2 = 2.0f * sat, bt2 = 2.0f * sbt;

        float o = opac[n];
        float bias = -flog2(1.0f + fexp2(-GV_LOG2E * o));

        float tv = ((float)t + 0.5f) * (2.0f / (float)GV_T) - 1.0f;
        float dt = tv - mt;

        const float k = K_HALF_LOG2E;
        A        = k * a;
        float B  = k * bb;
        float C  = k * ab2;
        float Dx = k * (at2 * dt - 2.0f * a * mx - ab2 * my);
        float Dy = k * (bt2 * dt - 2.0f * bb * my - ab2 * mx);
        float E  = k * (a * mx * mx + bb * my * my + cc * dt * dt
                        + ab2 * mx * my - at2 * mx * dt - bt2 * my * dt) + bias;

        gy0 = fmaf(C, y0r, Dx);
        gy1 = fmaf(C, y1r, Dx);
        h0  = fmaf(fmaf(B, y0r, Dy), y0r, E);
        h1  = fmaf(fmaf(B, y1r, Dy), y1r, E);
        sv  = fexp2(2.0f * A * GV_DX * GV_DX);

        float fr = feats[n * 3 + 0];
        float fg = feats[n * 3 + 1];
        fb       = feats[n * 3 + 2];
        unsigned hr = (unsigned)__half_as_ushort(__float2half_rn(fr))
                    | ((unsigned)__half_as_ushort(__float2half_rn(fg)) << 16);
        rgbits = __uint_as_float(hr);

        // exact tile-max of u over the 2 rows (concave in x, A < 0)
        float inv2A = 0.5f * frcp(A);
        float xs0 = fminf(fmaxf(-gy0 * inv2A, -1.0f), 1.0f);
        float xs1 = fminf(fmaxf(-gy1 * inv2A, -1.0f), 1.0f);
        float u0  = fmaf(fmaf(A, xs0, gy0), xs0, h0);
        float u1  = fmaf(fmaf(A, xs1, gy1), xs1, h1);
        keep = (fmaxf(u0, u1) > U_CULL);
    }

    // ballot-compaction (order-preserving -> deterministic)
    unsigned long long bm = __ballot((int)keep);
    int wprefix = __popcll(bm & ((1ull << lane) - 1ull));
    if (lane == 0) swt[wv] = (int)__popcll(bm);
    __syncthreads();

    int base = 0, M = 0;
    #pragma unroll
    for (int k2 = 0; k2 < 16; ++k2) {
        int c = swt[k2];
        if (k2 < wv) base += c;
        M += c;
    }
    if (keep) {
        float4* dst = (float4*)&stab[(base + wprefix) * 8];
        dst[0] = make_float4(A, gy0, gy1, h0);
        dst[1] = make_float4(h1, sv, rgbits, fb);
    }
    __syncthreads();

    // ---------------- Phase 2: splat over M survivors (ILP-2, packed) ------
    int oct  = lane & 15;         // 8-px x-run
    int row  = (lane >> 4) & 1;   // row within 2-row slab
    int half = lane >> 5;         // gaussian parity within wave's chunk

    float x0  = ((float)(oct * 8) + 0.5f) * GV_DX - 1.0f;
    float caa = 2.0f * x0 + GV_DX;            // r-arg: dx*(A*caa + gy)
    bool  r1  = (row == 1);

    int chunk = (M + 15) >> 4;
    int g0    = wv * chunk;
    int cnt_w = M - g0;
    if (cnt_w > chunk) cnt_w = chunk;
    if (cnt_w < 0) cnt_w = 0;

    f32x2 aR2[8], aG2[8], aB2[8];
    #pragma unroll
    for (int j = 0; j < 8; ++j) {
        aR2[j] = (f32x2)(0.f); aG2[j] = (f32x2)(0.f); aB2[j] = (f32x2)(0.f);
    }

    int i = half;
    #pragma unroll 1
    for (; i + 2 < cnt_w; i += 4) {
        const float4* qa = (const float4*)&stab[(g0 + i) * 8];
        const float4* qb = (const float4*)&stab[(g0 + i + 2) * 8];
        float4 va0 = qa[0], va1 = qa[1];  // A gy0 gy1 h0 | h1 s rg fb
        float4 vb0 = qb[0], vb1 = qb[1];

        float gya = r1 ? va0.z : va0.y;
        float gyb = r1 ? vb0.z : vb0.y;
        float ha  = r1 ? va1.x : va0.w;
        float hb  = r1 ? vb1.x : vb0.w;

        float ua = fmaf(fmaf(va0.x, x0, gya), x0, ha);
        float ub = fmaf(fmaf(vb0.x, x0, gyb), x0, hb);

        f32x2 e2 = { fexp2(ua), fexp2(ub) };
        f32x2 r2 = { fexp2(GV_DX * fmaf(va0.x, caa, gya)),
                     fexp2(GV_DX * fmaf(vb0.x, caa, gyb)) };
        f32x2 s2 = { va1.y, vb1.y };

        unsigned ba  = __float_as_uint(va1.z);
        unsigned bbb = __float_as_uint(vb1.z);
        f32x2 fr2 = { __half2float(__ushort_as_half((unsigned short)(ba & 0xffffu))),
                      __half2float(__ushort_as_half((unsigned short)(bbb & 0xffffu))) };
        f32x2 fg2 = { __half2float(__ushort_as_half((unsigned short)(ba >> 16))),
                      __half2float(__ushort_as_half((unsigned short)(bbb >> 16))) };
        f32x2 fb2 = { va1.w, vb1.w };

        #pragma unroll
        for (int j = 0; j < 8; ++j) {
            aR2[j] = __builtin_elementwise_fma(e2, fr2, aR2[j]);
            aG2[j] = __builtin_elementwise_fma(e2, fg2, aG2[j]);
            aB2[j] = __builtin_elementwise_fma(e2, fb2, aB2[j]);
            if (j < 7) { e2 *= r2; r2 *= s2; }
        }
    }
    if (i < cnt_w) {   // tail: single gaussian into component 0
        const float4* qr = (const float4*)&stab[(g0 + i) * 8];
        float4 v0 = qr[0];
        float4 v1 = qr[1];
        float gy = r1 ? v0.z : v0.y;
        float h  = r1 ? v1.x : v0.w;
        float u  = fmaf(fmaf(v0.x, x0, gy), x0, h);
        float e  = fexp2(u);
        float r  = fexp2(GV_DX * fmaf(v0.x, caa, gy));
        float s  = v1.y;
        unsigned bits = __float_as_uint(v1.z);
        float fr = __half2float(__ushort_as_half((unsigned short)(bits & 0xffffu)));
        float fg = __half2float(__ushort_as_half((unsigned short)(bits >> 16)));
        float fbv = v1.w;
        #pragma unroll
        for (int j = 0; j < 8; ++j) {
            aR2[j][0] = fmaf(e, fr,  aR2[j][0]);
            aG2[j][0] = fmaf(e, fg,  aG2[j][0]);
            aB2[j][0] = fmaf(e, fbv, aB2[j][0]);
            if (j < 7) { e *= r; r *= s; }
        }
    }

    // ---------------- Phase 3: block reduce + write -------------------------
    float aR[8], aG[8], aB[8];
    #pragma unroll
    for (int j = 0; j < 8; ++j) {
        aR[j] = aR2[j][0] + aR2[j][1];
        aG[j] = aG2[j][0] + aG2[j][1];
        aB[j] = aB2[j][0] + aB2[j][1];
        aR[j] += __shfl_xor(aR[j], 32, 64);
        aG[j] += __shfl_xor(aG[j], 32, 64);
        aB[j] += __shfl_xor(aB[j], 32, 64);
    }

    __syncthreads();  // record reads done; reuse stab for partial dump

    if (half == 0) {
        // slot stride 25 (coprime with 32 banks) -> conflict-free dump
        float* dst = &stab[(wv * 32 + (row * 16 + oct)) * 25];
        #pragma unroll
        for (int j = 0; j < 8; ++j) {
            dst[j * 3 + 0] = aR[j];
            dst[j * 3 + 1] = aG[j];
            dst[j * 3 + 2] = aB[j];
        }
    }
    __syncthreads();

    // final: 768 outputs; coalesced contiguous write
    if (tid < 2 * GV_W * 3) {
        int o  = tid;
        int c  = o % 3;
        int xr = o / 3;
        int x  = xr & 127;
        int rw = xr >> 7;
        int oc = x >> 3;
        int j  = x & 7;
        int ofs = (rw * 16 + oc) * 25 + j * 3 + c;
        float sacc = 0.f;
        #pragma unroll
        for (int wvI = 0; wvI < 16; ++wvI) sacc += stab[wvI * 800 + ofs];
        int basew = ((t * GV_H + slab * 2) * GV_W) * 3;
        out[basew + o] = fminf(fmaxf(sacc, 0.0f), 1.0f);
    }
}

extern "C" void kernel_launch(void* const* d_in, const int* in_sizes, int n_in,
                              void* d_out, int out_size, void* d_ws, size_t ws_size,
                              hipStream_t stream) {
    const float* xyz   = (const float*)d_in[0];
    const float* chol  = (const float*)d_in[1];
    const float* feats = (const float*)d_in[2];
    const float* opac  = (const float*)d_in[3];
    float* out = (float*)d_out;
    int N = in_sizes[0] / 3;
    if (N > GV_NMAX) N = GV_NMAX;  // LDS record capacity (reference N=1024)

    int blocks = GV_T * (GV_H / 2);  // 256: 64 slabs x 4 t
    gv_fused_kernel<<<blocks, 1024, 0, stream>>>(xyz, chol, feats, opac, out, N);
}